// Round 1
// baseline (2360.251 us; speedup 1.0000x reference)
//
#include <hip/hip_runtime.h>

// Problem constants (from reference setup_inputs)
constexpr int NUM_USER  = 100000;
constexpr int NUM_ITEM  = 50000;
constexpr int DIM       = 64;
constexpr int NUM_EDGES = 3200000;

// ---------------------------------------------------------------------------
// Index dtype detection: JAX under default config silently keeps int32 despite
// .astype(jnp.int64); harness contract hints int32. Detect on-device: if the
// buffer is int64 (values < 2^31), every odd int32 slot is 0. With 64 random
// indices checked, false positive probability is ~0.
// ---------------------------------------------------------------------------
__global__ void k_detect(const void* eu, const void* ei, int* flag) {
  if (threadIdx.x == 0 && blockIdx.x == 0) {
    const int* a = (const int*)eu;
    const int* b = (const int*)ei;
    int any = 0;
    for (int i = 1; i < 64; i += 2) { any |= a[i]; any |= b[i]; }
    *flag = (any == 0) ? 1 : 0;  // 1 => int64 layout
  }
}

__device__ __forceinline__ int idx_at(const void* p, int e, int is64) {
  if (is64) return (int)((const long long*)p)[e];
  return ((const int*)p)[e];
}

// ---------------------------------------------------------------------------
// Pass 1: per edge e: out0[eu,:] += item_emb[ei,:]; item_sum[ei,:] += user_emb[eu,:]
//         cnt_user[eu] += 1; cnt_item[ei] += 1
// Block = 256 threads = 4 edges x 64 dims. Grid-stride over edges.
// ---------------------------------------------------------------------------
__global__ void k_scatter1(const float* __restrict__ user_emb,
                           const float* __restrict__ item_emb,
                           const void* eu_p, const void* ei_p,
                           const int* __restrict__ flag,
                           float* out0, float* item_sum,
                           float* cnt_user, float* cnt_item) {
  const int is64 = *flag;
  const int lane = threadIdx.x & (DIM - 1);
  const int sub  = threadIdx.x >> 6;            // edge slot within block (0..3)
  const int epb  = blockDim.x >> 6;             // 4 edges per block-iteration
  for (int e = blockIdx.x * epb + sub; e < NUM_EDGES; e += gridDim.x * epb) {
    const int eu = idx_at(eu_p, e, is64);
    const int ei = idx_at(ei_p, e, is64);
    const float iv = item_emb[ei * DIM + lane];
    const float uv = user_emb[eu * DIM + lane];
    atomicAdd(&out0[eu * DIM + lane], iv);
    atomicAdd(&item_sum[ei * DIM + lane], uv);
    if (lane == 0) {
      atomicAdd(&cnt_user[eu], 1.0f);
      atomicAdd(&cnt_item[ei], 1.0f);
    }
  }
}

// item_sum[i,:] /= max(cnt_item[i], 1)   (in place -> becomes item_user_agg)
__global__ void k_div_item(float* item_sum, const float* __restrict__ cnt_item) {
  const int n = NUM_ITEM * DIM;
  for (int t = blockIdx.x * blockDim.x + threadIdx.x; t < n;
       t += gridDim.x * blockDim.x) {
    const float c = fmaxf(cnt_item[t >> 6], 1.0f);
    item_sum[t] /= c;
  }
}

// Pass 2: out1[eu,:] += item_user_agg[ei,:]
__global__ void k_scatter2(const float* __restrict__ item_agg,
                           const void* eu_p, const void* ei_p,
                           const int* __restrict__ flag,
                           float* out1) {
  const int is64 = *flag;
  const int lane = threadIdx.x & (DIM - 1);
  const int sub  = threadIdx.x >> 6;
  const int epb  = blockDim.x >> 6;
  for (int e = blockIdx.x * epb + sub; e < NUM_EDGES; e += gridDim.x * epb) {
    const int eu = idx_at(eu_p, e, is64);
    const int ei = idx_at(ei_p, e, is64);
    atomicAdd(&out1[eu * DIM + lane], item_agg[ei * DIM + lane]);
  }
}

// out0[u,:] /= max(cnt_user[u],1); out1[u,:] /= max(cnt_user[u],1)
__global__ void k_finalize(float* out0, float* out1,
                           const float* __restrict__ cnt_user) {
  const int n = NUM_USER * DIM;
  for (int t = blockIdx.x * blockDim.x + threadIdx.x; t < n;
       t += gridDim.x * blockDim.x) {
    const float c = fmaxf(cnt_user[t >> 6], 1.0f);
    out0[t] /= c;
    out1[t] /= c;
  }
}

extern "C" void kernel_launch(void* const* d_in, const int* in_sizes, int n_in,
                              void* d_out, int out_size, void* d_ws, size_t ws_size,
                              hipStream_t stream) {
  const float* user_emb = (const float*)d_in[0];
  const float* item_emb = (const float*)d_in[1];
  const void*  eu_p     = d_in[2];
  const void*  ei_p     = d_in[3];

  float* out0 = (float*)d_out;                       // neighbor_feat
  float* out1 = out0 + (size_t)NUM_USER * DIM;       // cooccur_feat

  // Workspace layout (floats)
  float* ws       = (float*)d_ws;
  float* item_sum = ws;                              // NUM_ITEM*DIM = 3,200,000
  float* cnt_user = ws + (size_t)NUM_ITEM * DIM;     // 100,000
  float* cnt_item = cnt_user + NUM_USER;             // 50,000
  int*   flag     = (int*)(cnt_item + NUM_ITEM);     // 1

  const size_t ws_used_bytes =
      ((size_t)NUM_ITEM * DIM + NUM_USER + NUM_ITEM + 1) * sizeof(float);

  // Zero accumulators every call (harness poisons once with 0xAA).
  hipMemsetAsync(d_out, 0, (size_t)out_size * sizeof(float), stream);
  hipMemsetAsync(d_ws, 0, ws_used_bytes, stream);

  k_detect<<<1, 64, 0, stream>>>(eu_p, ei_p, flag);

  const int threads = 256;
  const int sgrid = 4096;  // grid-stride over 3.2M edges, 4 edges/block-iter
  k_scatter1<<<sgrid, threads, 0, stream>>>(user_emb, item_emb, eu_p, ei_p, flag,
                                            out0, item_sum, cnt_user, cnt_item);

  k_div_item<<<2048, threads, 0, stream>>>(item_sum, cnt_item);

  k_scatter2<<<sgrid, threads, 0, stream>>>(item_sum, eu_p, ei_p, flag, out1);

  k_finalize<<<2048, threads, 0, stream>>>(out0, out1, cnt_user);
}

// Round 2
// 1179.344 us; speedup vs baseline: 2.0013x; 2.0013x over previous
//
#include <hip/hip_runtime.h>

constexpr int NUM_USER  = 100000;
constexpr int NUM_ITEM  = 50000;
constexpr int DIM       = 64;
constexpr int NUM_EDGES = 3200000;

// ---------------------------------------------------------------------------
// Index dtype detection (int64 buffers have all-zero high words).
// ---------------------------------------------------------------------------
__global__ void k_detect(const void* eu, const void* ei, int* flag) {
  if (threadIdx.x == 0 && blockIdx.x == 0) {
    const int* a = (const int*)eu;
    const int* b = (const int*)ei;
    int any = 0;
    for (int i = 1; i < 64; i += 2) { any |= a[i]; any |= b[i]; }
    *flag = (any == 0) ? 1 : 0;  // 1 => int64 layout
  }
}

__device__ __forceinline__ int idx_at(const void* p, int e, int is64) {
  // little-endian: low word of the int64 holds the value
  return is64 ? ((const int*)p)[2 * e] : ((const int*)p)[e];
}

// ---------------------------------------------------------------------------
// CSR build: histogram -> exclusive scan -> slot fill
// ---------------------------------------------------------------------------
__global__ void k_hist(const void* eu_p, const void* ei_p,
                       const int* __restrict__ flag,
                       int* cnt_u, int* cnt_i) {
  const int is64 = *flag;
  for (int e = blockIdx.x * blockDim.x + threadIdx.x; e < NUM_EDGES;
       e += gridDim.x * blockDim.x) {
    atomicAdd(&cnt_u[idx_at(eu_p, e, is64)], 1);
    atomicAdd(&cnt_i[idx_at(ei_p, e, is64)], 1);
  }
}

// Single-workgroup exclusive scan of n ints (n <= 1024*1024). out has n+1 slots.
__global__ void k_scan(const int* __restrict__ in, int* __restrict__ out, int n) {
  __shared__ int part[1024];
  const int t = threadIdx.x;
  const int chunk = (n + 1023) >> 10;
  const int lo = t * chunk;
  const int hi = min(lo + chunk, n);
  int s = 0;
  for (int i = lo; i < hi; ++i) s += in[i];
  part[t] = s;
  __syncthreads();
  for (int d = 1; d < 1024; d <<= 1) {
    int v = (t >= d) ? part[t - d] : 0;
    __syncthreads();
    part[t] += v;
    __syncthreads();
  }
  int run = (t == 0) ? 0 : part[t - 1];
  for (int i = lo; i < hi; ++i) { int v = in[i]; out[i] = run; run += v; }
  if (t == 1023) out[n] = part[1023];
}

__global__ void k_fill(const void* eu_p, const void* ei_p,
                       const int* __restrict__ flag,
                       const int* __restrict__ rs_u, const int* __restrict__ rs_i,
                       int* cur_u, int* cur_i,
                       int* ei_sorted, int* eu_sorted) {
  const int is64 = *flag;
  for (int e = blockIdx.x * blockDim.x + threadIdx.x; e < NUM_EDGES;
       e += gridDim.x * blockDim.x) {
    const int eu = idx_at(eu_p, e, is64);
    const int ei = idx_at(ei_p, e, is64);
    const int pu = rs_u[eu] + atomicAdd(&cur_u[eu], 1);
    ei_sorted[pu] = ei;
    const int pi = rs_i[ei] + atomicAdd(&cur_i[ei], 1);
    eu_sorted[pi] = eu;
  }
}

// ---------------------------------------------------------------------------
// Gather kernels: one wave (64 lanes = 64 dims) per segment, 4 segments/block
// ---------------------------------------------------------------------------
__global__ void k_item_agg(const float* __restrict__ user_emb,
                           const int* __restrict__ eu_sorted,
                           const int* __restrict__ rs_i,
                           float* __restrict__ item_agg) {
  const int lane = threadIdx.x & (DIM - 1);
  const int seg = blockIdx.x * (blockDim.x >> 6) + (threadIdx.x >> 6);
  if (seg >= NUM_ITEM) return;
  const int lo = rs_i[seg], hi = rs_i[seg + 1];
  float s = 0.f;
  int j = lo;
  for (; j + 3 < hi; j += 4) {
    const int i0 = eu_sorted[j], i1 = eu_sorted[j + 1];
    const int i2 = eu_sorted[j + 2], i3 = eu_sorted[j + 3];
    s += user_emb[(size_t)i0 * DIM + lane];
    s += user_emb[(size_t)i1 * DIM + lane];
    s += user_emb[(size_t)i2 * DIM + lane];
    s += user_emb[(size_t)i3 * DIM + lane];
  }
  for (; j < hi; ++j) s += user_emb[(size_t)eu_sorted[j] * DIM + lane];
  const float c = fmaxf((float)(hi - lo), 1.0f);
  item_agg[(size_t)seg * DIM + lane] = s / c;
}

__global__ void k_user_gather(const float* __restrict__ item_emb,
                              const float* __restrict__ item_agg,
                              const int* __restrict__ ei_sorted,
                              const int* __restrict__ rs_u,
                              float* __restrict__ out0,
                              float* __restrict__ out1) {
  const int lane = threadIdx.x & (DIM - 1);
  const int seg = blockIdx.x * (blockDim.x >> 6) + (threadIdx.x >> 6);
  if (seg >= NUM_USER) return;
  const int lo = rs_u[seg], hi = rs_u[seg + 1];
  float s0 = 0.f, s1 = 0.f;
  int j = lo;
  for (; j + 3 < hi; j += 4) {
    const int i0 = ei_sorted[j], i1 = ei_sorted[j + 1];
    const int i2 = ei_sorted[j + 2], i3 = ei_sorted[j + 3];
    s0 += item_emb[(size_t)i0 * DIM + lane];
    s0 += item_emb[(size_t)i1 * DIM + lane];
    s0 += item_emb[(size_t)i2 * DIM + lane];
    s0 += item_emb[(size_t)i3 * DIM + lane];
    s1 += item_agg[(size_t)i0 * DIM + lane];
    s1 += item_agg[(size_t)i1 * DIM + lane];
    s1 += item_agg[(size_t)i2 * DIM + lane];
    s1 += item_agg[(size_t)i3 * DIM + lane];
  }
  for (; j < hi; ++j) {
    const int i0 = ei_sorted[j];
    s0 += item_emb[(size_t)i0 * DIM + lane];
    s1 += item_agg[(size_t)i0 * DIM + lane];
  }
  const float c = fmaxf((float)(hi - lo), 1.0f);
  out0[(size_t)seg * DIM + lane] = s0 / c;
  out1[(size_t)seg * DIM + lane] = s1 / c;
}

// ---------------------------------------------------------------------------
// Fallback path (round-0 atomic scatter) if ws is too small for CSR.
// ---------------------------------------------------------------------------
__global__ void k_scatter1(const float* __restrict__ user_emb,
                           const float* __restrict__ item_emb,
                           const void* eu_p, const void* ei_p,
                           const int* __restrict__ flag,
                           float* out0, float* item_sum,
                           float* cnt_user, float* cnt_item) {
  const int is64 = *flag;
  const int lane = threadIdx.x & (DIM - 1);
  const int sub  = threadIdx.x >> 6;
  const int epb  = blockDim.x >> 6;
  for (int e = blockIdx.x * epb + sub; e < NUM_EDGES; e += gridDim.x * epb) {
    const int eu = idx_at(eu_p, e, is64);
    const int ei = idx_at(ei_p, e, is64);
    atomicAdd(&out0[eu * DIM + lane], item_emb[ei * DIM + lane]);
    atomicAdd(&item_sum[ei * DIM + lane], user_emb[eu * DIM + lane]);
    if (lane == 0) {
      atomicAdd(&cnt_user[eu], 1.0f);
      atomicAdd(&cnt_item[ei], 1.0f);
    }
  }
}

__global__ void k_div_item(float* item_sum, const float* __restrict__ cnt_item) {
  const int n = NUM_ITEM * DIM;
  for (int t = blockIdx.x * blockDim.x + threadIdx.x; t < n;
       t += gridDim.x * blockDim.x)
    item_sum[t] /= fmaxf(cnt_item[t >> 6], 1.0f);
}

__global__ void k_scatter2(const float* __restrict__ item_agg,
                           const void* eu_p, const void* ei_p,
                           const int* __restrict__ flag, float* out1) {
  const int is64 = *flag;
  const int lane = threadIdx.x & (DIM - 1);
  const int sub  = threadIdx.x >> 6;
  const int epb  = blockDim.x >> 6;
  for (int e = blockIdx.x * epb + sub; e < NUM_EDGES; e += gridDim.x * epb) {
    const int eu = idx_at(eu_p, e, is64);
    const int ei = idx_at(ei_p, e, is64);
    atomicAdd(&out1[eu * DIM + lane], item_agg[ei * DIM + lane]);
  }
}

__global__ void k_finalize(float* out0, float* out1,
                           const float* __restrict__ cnt_user) {
  const int n = NUM_USER * DIM;
  for (int t = blockIdx.x * blockDim.x + threadIdx.x; t < n;
       t += gridDim.x * blockDim.x) {
    const float c = fmaxf(cnt_user[t >> 6], 1.0f);
    out0[t] /= c;
    out1[t] /= c;
  }
}

// ---------------------------------------------------------------------------
extern "C" void kernel_launch(void* const* d_in, const int* in_sizes, int n_in,
                              void* d_out, int out_size, void* d_ws, size_t ws_size,
                              hipStream_t stream) {
  const float* user_emb = (const float*)d_in[0];
  const float* item_emb = (const float*)d_in[1];
  const void*  eu_p     = d_in[2];
  const void*  ei_p     = d_in[3];

  float* out0 = (float*)d_out;
  float* out1 = out0 + (size_t)NUM_USER * DIM;

  // CSR-path workspace layout (4B units)
  const size_t o_item_agg  = 0;                                 // 3,200,000 f32
  const size_t o_ei_sorted = o_item_agg + (size_t)NUM_ITEM * DIM;   // 3.2M int
  const size_t o_eu_sorted = o_ei_sorted + NUM_EDGES;               // 3.2M int
  const size_t o_rs_u      = o_eu_sorted + NUM_EDGES;               // 100001
  const size_t o_rs_i      = o_rs_u + NUM_USER + 1;                 // 50001
  const size_t o_cur_u     = o_rs_i + NUM_ITEM + 1;                 // 100000
  const size_t o_cur_i     = o_cur_u + NUM_USER;                    // 50000
  const size_t o_flag      = o_cur_i + NUM_ITEM;                    // 1
  const size_t need_bytes  = (o_flag + 1) * 4;

  int* wsi = (int*)d_ws;
  float* wsf = (float*)d_ws;

  if (ws_size >= need_bytes) {
    float* item_agg  = wsf + o_item_agg;
    int* ei_sorted   = wsi + o_ei_sorted;
    int* eu_sorted   = wsi + o_eu_sorted;
    int* rs_u        = wsi + o_rs_u;
    int* rs_i        = wsi + o_rs_i;
    int* cur_u       = wsi + o_cur_u;
    int* cur_i       = wsi + o_cur_i;
    int* flag        = wsi + o_flag;

    k_detect<<<1, 64, 0, stream>>>(eu_p, ei_p, flag);

    // zero cursors (used as histogram counters first)
    hipMemsetAsync(cur_u, 0, (size_t)(NUM_USER + NUM_ITEM) * 4, stream);
    k_hist<<<6400, 512, 0, stream>>>(eu_p, ei_p, flag, cur_u, cur_i);
    k_scan<<<1, 1024, 0, stream>>>(cur_u, rs_u, NUM_USER);
    k_scan<<<1, 1024, 0, stream>>>(cur_i, rs_i, NUM_ITEM);
    hipMemsetAsync(cur_u, 0, (size_t)(NUM_USER + NUM_ITEM) * 4, stream);
    k_fill<<<6400, 512, 0, stream>>>(eu_p, ei_p, flag, rs_u, rs_i,
                                     cur_u, cur_i, ei_sorted, eu_sorted);

    k_item_agg<<<(NUM_ITEM + 3) / 4, 256, 0, stream>>>(user_emb, eu_sorted,
                                                       rs_i, item_agg);
    k_user_gather<<<(NUM_USER + 3) / 4, 256, 0, stream>>>(item_emb, item_agg,
                                                          ei_sorted, rs_u,
                                                          out0, out1);
  } else {
    // fallback: round-0 atomic path (needs ~13 MB)
    float* item_sum = wsf;
    float* cnt_user = wsf + (size_t)NUM_ITEM * DIM;
    float* cnt_item = cnt_user + NUM_USER;
    int*   flag     = (int*)(cnt_item + NUM_ITEM);
    const size_t used = ((size_t)NUM_ITEM * DIM + NUM_USER + NUM_ITEM + 1) * 4;

    hipMemsetAsync(d_out, 0, (size_t)out_size * sizeof(float), stream);
    hipMemsetAsync(d_ws, 0, used, stream);
    k_detect<<<1, 64, 0, stream>>>(eu_p, ei_p, flag);
    k_scatter1<<<4096, 256, 0, stream>>>(user_emb, item_emb, eu_p, ei_p, flag,
                                         out0, item_sum, cnt_user, cnt_item);
    k_div_item<<<2048, 256, 0, stream>>>(item_sum, cnt_item);
    k_scatter2<<<4096, 256, 0, stream>>>(item_sum, eu_p, ei_p, flag, out1);
    k_finalize<<<2048, 256, 0, stream>>>(out0, out1, cnt_user);
  }
}

// Round 3
// 991.342 us; speedup vs baseline: 2.3809x; 1.1896x over previous
//
#include <hip/hip_runtime.h>

constexpr int NUM_USER  = 100000;
constexpr int NUM_ITEM  = 50000;
constexpr int DIM       = 64;
constexpr int NUM_EDGES = 3200000;

// ---------------------------------------------------------------------------
// bf16 helpers (RNE round; inputs are finite normals, no NaN care needed)
// ---------------------------------------------------------------------------
__device__ __forceinline__ float bf2f(unsigned short u) {
  union { unsigned int i; float f; } v; v.i = (unsigned int)u << 16; return v.f;
}
__device__ __forceinline__ unsigned short f2bf(float x) {
  union { float f; unsigned int i; } v; v.f = x;
  unsigned int r = v.i + 0x7FFFu + ((v.i >> 16) & 1u);
  return (unsigned short)(r >> 16);
}

// ---------------------------------------------------------------------------
// Index dtype detection (int64 buffers have all-zero high words).
// ---------------------------------------------------------------------------
__global__ void k_detect(const void* eu, const void* ei, int* flag) {
  if (threadIdx.x == 0 && blockIdx.x == 0) {
    const int* a = (const int*)eu;
    const int* b = (const int*)ei;
    int any = 0;
    for (int i = 1; i < 64; i += 2) { any |= a[i]; any |= b[i]; }
    *flag = (any == 0) ? 1 : 0;  // 1 => int64 layout
  }
}

__device__ __forceinline__ int idx_at(const void* p, int e, int is64) {
  return is64 ? ((const int*)p)[2 * e] : ((const int*)p)[e];
}

// ---------------------------------------------------------------------------
// Embedding f32 -> bf16 conversion (both tables in one grid-stride kernel)
// ---------------------------------------------------------------------------
__global__ void k_cvt_emb(const float* __restrict__ user_emb,
                          const float* __restrict__ item_emb,
                          unsigned short* __restrict__ user16,
                          unsigned short* __restrict__ item16) {
  const int nu4 = NUM_USER * DIM / 4;   // 1.6M float4 for users
  const int ni4 = NUM_ITEM * DIM / 4;   // 0.8M float4 for items
  const int n4 = nu4 + ni4;
  for (int t = blockIdx.x * blockDim.x + threadIdx.x; t < n4;
       t += gridDim.x * blockDim.x) {
    const float4 v = (t < nu4) ? ((const float4*)user_emb)[t]
                               : ((const float4*)item_emb)[t - nu4];
    ushort4 o;
    o.x = f2bf(v.x); o.y = f2bf(v.y); o.z = f2bf(v.z); o.w = f2bf(v.w);
    if (t < nu4) ((ushort4*)user16)[t] = o;
    else         ((ushort4*)item16)[t - nu4] = o;
  }
}

// ---------------------------------------------------------------------------
// Histogram of both endpoint arrays
// ---------------------------------------------------------------------------
__global__ void k_hist(const void* eu_p, const void* ei_p,
                       const int* __restrict__ flag,
                       int* cnt_u, int* cnt_i) {
  const int is64 = *flag;
  for (int e = blockIdx.x * blockDim.x + threadIdx.x; e < NUM_EDGES;
       e += gridDim.x * blockDim.x) {
    atomicAdd(&cnt_u[idx_at(eu_p, e, is64)], 1);
    atomicAdd(&cnt_i[idx_at(ei_p, e, is64)], 1);
  }
}

// ---------------------------------------------------------------------------
// Fused exclusive scans: block 0 -> users, block 1 -> items
// ---------------------------------------------------------------------------
__device__ void scan_body(const int* __restrict__ in, int* __restrict__ out,
                          int n) {
  __shared__ int part[1024];
  const int t = threadIdx.x;
  const int chunk = (n + 1023) >> 10;
  const int lo = min(t * chunk, n);
  const int hi = min(lo + chunk, n);
  int s = 0;
  for (int i = lo; i < hi; ++i) s += in[i];
  part[t] = s;
  __syncthreads();
  for (int d = 1; d < 1024; d <<= 1) {
    int v = (t >= d) ? part[t - d] : 0;
    __syncthreads();
    part[t] += v;
    __syncthreads();
  }
  int run = (t == 0) ? 0 : part[t - 1];
  for (int i = lo; i < hi; ++i) { int v = in[i]; out[i] = run; run += v; }
  if (t == 1023) out[n] = part[1023];
}

__global__ void k_scan2(const int* __restrict__ cnt_u, int* __restrict__ rs_u,
                        const int* __restrict__ cnt_i, int* __restrict__ rs_i) {
  if (blockIdx.x == 0) scan_body(cnt_u, rs_u, NUM_USER);
  else                 scan_body(cnt_i, rs_i, NUM_ITEM);
}

// ---------------------------------------------------------------------------
// Fill: item-grouped list of users (into shared sorted buffer)
// ---------------------------------------------------------------------------
__global__ void k_fill_item(const void* eu_p, const void* ei_p,
                            const int* __restrict__ flag,
                            const int* __restrict__ rs_i, int* cur_i,
                            int* __restrict__ sorted) {
  const int is64 = *flag;
  for (int e = blockIdx.x * blockDim.x + threadIdx.x; e < NUM_EDGES;
       e += gridDim.x * blockDim.x) {
    const int eu = idx_at(eu_p, e, is64);
    const int ei = idx_at(ei_p, e, is64);
    const int pi = rs_i[ei] + atomicAdd(&cur_i[ei], 1);
    sorted[pi] = eu;
  }
}

// Fill: user-grouped list of items (REUSES the same sorted buffer)
__global__ void k_fill_user(const void* eu_p, const void* ei_p,
                            const int* __restrict__ flag,
                            const int* __restrict__ rs_u, int* cur_u,
                            int* __restrict__ sorted) {
  const int is64 = *flag;
  for (int e = blockIdx.x * blockDim.x + threadIdx.x; e < NUM_EDGES;
       e += gridDim.x * blockDim.x) {
    const int eu = idx_at(eu_p, e, is64);
    const int ei = idx_at(ei_p, e, is64);
    const int pu = rs_u[eu] + atomicAdd(&cur_u[eu], 1);
    sorted[pu] = ei;
  }
}

// ---------------------------------------------------------------------------
// item_agg[i,:] = mean of user16 rows for item i  (bf16 in, bf16 out)
// one wave (64 lanes = 64 dims) per segment, 4 segments per 256-block
// ---------------------------------------------------------------------------
__global__ void k_item_agg(const unsigned short* __restrict__ user16,
                           const int* __restrict__ eu_sorted,
                           const int* __restrict__ rs_i,
                           unsigned short* __restrict__ item_agg16) {
  const int lane = threadIdx.x & (DIM - 1);
  const int seg = blockIdx.x * (blockDim.x >> 6) + (threadIdx.x >> 6);
  if (seg >= NUM_ITEM) return;
  const int lo = rs_i[seg], hi = rs_i[seg + 1];
  float s = 0.f;
  int j = lo;
  for (; j + 3 < hi; j += 4) {
    const int i0 = eu_sorted[j], i1 = eu_sorted[j + 1];
    const int i2 = eu_sorted[j + 2], i3 = eu_sorted[j + 3];
    s += bf2f(user16[(size_t)i0 * DIM + lane]);
    s += bf2f(user16[(size_t)i1 * DIM + lane]);
    s += bf2f(user16[(size_t)i2 * DIM + lane]);
    s += bf2f(user16[(size_t)i3 * DIM + lane]);
  }
  for (; j < hi; ++j) s += bf2f(user16[(size_t)eu_sorted[j] * DIM + lane]);
  const float c = fmaxf((float)(hi - lo), 1.0f);
  item_agg16[(size_t)seg * DIM + lane] = f2bf(s / c);
}

// ---------------------------------------------------------------------------
// Per user: out0 = mean item16 rows, out1 = mean item_agg16 rows
// ---------------------------------------------------------------------------
__global__ void k_user_gather(const unsigned short* __restrict__ item16,
                              const unsigned short* __restrict__ item_agg16,
                              const int* __restrict__ ei_sorted,
                              const int* __restrict__ rs_u,
                              float* __restrict__ out0,
                              float* __restrict__ out1) {
  const int lane = threadIdx.x & (DIM - 1);
  const int seg = blockIdx.x * (blockDim.x >> 6) + (threadIdx.x >> 6);
  if (seg >= NUM_USER) return;
  const int lo = rs_u[seg], hi = rs_u[seg + 1];
  float s0 = 0.f, s1 = 0.f;
  int j = lo;
  for (; j + 3 < hi; j += 4) {
    const int i0 = ei_sorted[j], i1 = ei_sorted[j + 1];
    const int i2 = ei_sorted[j + 2], i3 = ei_sorted[j + 3];
    s0 += bf2f(item16[(size_t)i0 * DIM + lane]);
    s0 += bf2f(item16[(size_t)i1 * DIM + lane]);
    s0 += bf2f(item16[(size_t)i2 * DIM + lane]);
    s0 += bf2f(item16[(size_t)i3 * DIM + lane]);
    s1 += bf2f(item_agg16[(size_t)i0 * DIM + lane]);
    s1 += bf2f(item_agg16[(size_t)i1 * DIM + lane]);
    s1 += bf2f(item_agg16[(size_t)i2 * DIM + lane]);
    s1 += bf2f(item_agg16[(size_t)i3 * DIM + lane]);
  }
  for (; j < hi; ++j) {
    const int i0 = ei_sorted[j];
    s0 += bf2f(item16[(size_t)i0 * DIM + lane]);
    s1 += bf2f(item_agg16[(size_t)i0 * DIM + lane]);
  }
  const float inv = 1.0f / fmaxf((float)(hi - lo), 1.0f);
  out0[(size_t)seg * DIM + lane] = s0 * inv;
  out1[(size_t)seg * DIM + lane] = s1 * inv;
}

// ---------------------------------------------------------------------------
// Fallback path (round-0 atomic scatter) if ws too small
// ---------------------------------------------------------------------------
__global__ void k_scatter1(const float* __restrict__ user_emb,
                           const float* __restrict__ item_emb,
                           const void* eu_p, const void* ei_p,
                           const int* __restrict__ flag,
                           float* out0, float* item_sum,
                           float* cnt_user, float* cnt_item) {
  const int is64 = *flag;
  const int lane = threadIdx.x & (DIM - 1);
  const int sub  = threadIdx.x >> 6;
  const int epb  = blockDim.x >> 6;
  for (int e = blockIdx.x * epb + sub; e < NUM_EDGES; e += gridDim.x * epb) {
    const int eu = idx_at(eu_p, e, is64);
    const int ei = idx_at(ei_p, e, is64);
    atomicAdd(&out0[eu * DIM + lane], item_emb[ei * DIM + lane]);
    atomicAdd(&item_sum[ei * DIM + lane], user_emb[eu * DIM + lane]);
    if (lane == 0) {
      atomicAdd(&cnt_user[eu], 1.0f);
      atomicAdd(&cnt_item[ei], 1.0f);
    }
  }
}

__global__ void k_div_item(float* item_sum, const float* __restrict__ cnt_item) {
  const int n = NUM_ITEM * DIM;
  for (int t = blockIdx.x * blockDim.x + threadIdx.x; t < n;
       t += gridDim.x * blockDim.x)
    item_sum[t] /= fmaxf(cnt_item[t >> 6], 1.0f);
}

__global__ void k_scatter2(const float* __restrict__ item_agg,
                           const void* eu_p, const void* ei_p,
                           const int* __restrict__ flag, float* out1) {
  const int is64 = *flag;
  const int lane = threadIdx.x & (DIM - 1);
  const int sub  = threadIdx.x >> 6;
  const int epb  = blockDim.x >> 6;
  for (int e = blockIdx.x * epb + sub; e < NUM_EDGES; e += gridDim.x * epb) {
    const int eu = idx_at(eu_p, e, is64);
    const int ei = idx_at(ei_p, e, is64);
    atomicAdd(&out1[eu * DIM + lane], item_agg[ei * DIM + lane]);
  }
}

__global__ void k_finalize(float* out0, float* out1,
                           const float* __restrict__ cnt_user) {
  const int n = NUM_USER * DIM;
  for (int t = blockIdx.x * blockDim.x + threadIdx.x; t < n;
       t += gridDim.x * blockDim.x) {
    const float c = fmaxf(cnt_user[t >> 6], 1.0f);
    out0[t] /= c;
    out1[t] /= c;
  }
}

// ---------------------------------------------------------------------------
extern "C" void kernel_launch(void* const* d_in, const int* in_sizes, int n_in,
                              void* d_out, int out_size, void* d_ws, size_t ws_size,
                              hipStream_t stream) {
  const float* user_emb = (const float*)d_in[0];
  const float* item_emb = (const float*)d_in[1];
  const void*  eu_p     = d_in[2];
  const void*  ei_p     = d_in[3];

  float* out0 = (float*)d_out;
  float* out1 = out0 + (size_t)NUM_USER * DIM;

  // Workspace layout (4B units). Total = 9,900,003 * 4 B = 39.6 MB
  // (same footprint as R1's proven allocation).
  const size_t o_sorted  = 0;                                  // 3.2M int (shared!)
  const size_t o_user16  = o_sorted + NUM_EDGES;               // 6.4M bf16 = 3.2M u32
  const size_t o_item16  = o_user16 + (size_t)NUM_USER * DIM / 2;  // 3.2M bf16
  const size_t o_agg16   = o_item16 + (size_t)NUM_ITEM * DIM / 2;  // 3.2M bf16
  const size_t o_rs_u    = o_agg16 + (size_t)NUM_ITEM * DIM / 2;   // 100001
  const size_t o_rs_i    = o_rs_u + NUM_USER + 1;                  // 50001
  const size_t o_cur_u   = o_rs_i + NUM_ITEM + 1;                  // 100000
  const size_t o_cur_i   = o_cur_u + NUM_USER;                     // 50000
  const size_t o_flag    = o_cur_i + NUM_ITEM;                     // 1
  const size_t need_bytes = (o_flag + 1) * 4;

  int* wsi = (int*)d_ws;
  float* wsf = (float*)d_ws;

  if (ws_size >= need_bytes) {
    int* sorted = wsi + o_sorted;
    unsigned short* user16 = (unsigned short*)(wsi + o_user16);
    unsigned short* item16 = (unsigned short*)(wsi + o_item16);
    unsigned short* agg16  = (unsigned short*)(wsi + o_agg16);
    int* rs_u  = wsi + o_rs_u;
    int* rs_i  = wsi + o_rs_i;
    int* cur_u = wsi + o_cur_u;
    int* cur_i = wsi + o_cur_i;
    int* flag  = wsi + o_flag;

    k_detect<<<1, 64, 0, stream>>>(eu_p, ei_p, flag);
    k_cvt_emb<<<2048, 256, 0, stream>>>(user_emb, item_emb, user16, item16);

    hipMemsetAsync(cur_u, 0, (size_t)(NUM_USER + NUM_ITEM) * 4, stream);
    k_hist<<<6400, 512, 0, stream>>>(eu_p, ei_p, flag, cur_u, cur_i);
    k_scan2<<<2, 1024, 0, stream>>>(cur_u, rs_u, cur_i, rs_i);
    hipMemsetAsync(cur_u, 0, (size_t)(NUM_USER + NUM_ITEM) * 4, stream);

    // item-grouped sort -> item_agg (bf16), then reuse buffer for user sort
    k_fill_item<<<6400, 512, 0, stream>>>(eu_p, ei_p, flag, rs_i, cur_i, sorted);
    k_item_agg<<<(NUM_ITEM + 3) / 4, 256, 0, stream>>>(user16, sorted, rs_i, agg16);
    k_fill_user<<<6400, 512, 0, stream>>>(eu_p, ei_p, flag, rs_u, cur_u, sorted);
    k_user_gather<<<(NUM_USER + 3) / 4, 256, 0, stream>>>(item16, agg16, sorted,
                                                          rs_u, out0, out1);
  } else {
    // fallback: round-0 atomic path (needs ~13 MB)
    float* item_sum = wsf;
    float* cnt_user = wsf + (size_t)NUM_ITEM * DIM;
    float* cnt_item = cnt_user + NUM_USER;
    int*   flag     = (int*)(cnt_item + NUM_ITEM);
    const size_t used = ((size_t)NUM_ITEM * DIM + NUM_USER + NUM_ITEM + 1) * 4;

    hipMemsetAsync(d_out, 0, (size_t)out_size * sizeof(float), stream);
    hipMemsetAsync(d_ws, 0, used, stream);
    k_detect<<<1, 64, 0, stream>>>(eu_p, ei_p, flag);
    k_scatter1<<<4096, 256, 0, stream>>>(user_emb, item_emb, eu_p, ei_p, flag,
                                         out0, item_sum, cnt_user, cnt_item);
    k_div_item<<<2048, 256, 0, stream>>>(item_sum, cnt_item);
    k_scatter2<<<4096, 256, 0, stream>>>(item_sum, eu_p, ei_p, flag, out1);
    k_finalize<<<2048, 256, 0, stream>>>(out0, out1, cnt_user);
  }
}